// Round 2
// baseline (294.926 us; speedup 1.0000x reference)
//
#include <hip/hip_runtime.h>

constexpr int Zn = 20000;
constexpr int Un = 128;
constexpr int Sn = 8;
constexpr int Pn = 64;
constexpr int ROW = Sn * Un;          // 1024 floats per (z, tensor)
constexpr int ZPB = 2;                // z rows per block buffer
constexpr int NZP = Zn / ZPB;         // 10000 z-pair rounds
constexpr int THREADS = 256;          // 4 waves; wave w owns segments {2w, 2w+1}
constexpr int GRID = 1536;            // 6 blocks/CU x 256 CU -> persistent

// ---------------------------------------------------------------------------
// Prep: one wave, one lane per path. Counting-sort by i3 via ballot/popc.
// Table entries hold LDS float offsets for layout [t][z][1024] and coef.
// ---------------------------------------------------------------------------
__global__ __launch_bounds__(64) void prep_kernel(const int* __restrict__ pi,
                                                  const float* __restrict__ pc,
                                                  int4* __restrict__ table,
                                                  int* __restrict__ segstart) {
    const int p = threadIdx.x & 63;
    const int i0 = pi[4 * p + 0];
    const int i1 = pi[4 * p + 1];
    const int i2 = pi[4 * p + 2];
    const int i3 = pi[4 * p + 3];
    const float w = pc[p];
    const unsigned long long below = (1ull << p) - 1ull;

    int base = 0, slot = 0;
#pragma unroll
    for (int s = 0; s < Sn; ++s) {
        unsigned long long m = __ballot(i3 == s);
        if (i3 == s) slot = base + __popcll(m & below);
        if (p == 0) segstart[s] = base;
        base += __popcll(m);
    }
    if (p == 0) segstart[Sn] = base;   // == 64

    table[slot] = make_int4(i0 * Un,                    // tensor0: offset 0
                            ZPB * ROW + i1 * Un,        // tensor1 block base
                            2 * ZPB * ROW + i2 * Un,    // tensor2 block base
                            __float_as_int(w));
}

// ---------------------------------------------------------------------------
// Main: PERSISTENT blocks (grid=1536 -> 6 blocks/CU, 24 waves/CU). Each block
// grid-strides over ~6.5 z-pairs; per round the NEXT pair's 6 global_load
// dwordx4 are issued into registers BEFORE computing the current LDS-resident
// pair (T14 issue-early/write-late), so HBM latency hides under compute and
// the LDS pipe (the binding resource, ~37 us floor) stays continuously fed.
// k-loop is software-pipelined 1 iteration deep on the ds_reads.
// ---------------------------------------------------------------------------
__global__ __launch_bounds__(THREADS, 6) void tp_kernel(
        const float* __restrict__ x0,
        const float* __restrict__ x1,
        const float* __restrict__ x2,
        const int4* __restrict__ table,
        const int* __restrict__ segstart,
        float* __restrict__ out) {
    __shared__ __align__(16) float lds[3 * ZPB * ROW];   // 24 KB, [t][z][1024]
    const int tid  = threadIdx.x;
    const int lane = tid & 63;
    const int wave = tid >> 6;                   // 0..3: two segments each
    const int zloc = lane >> 5;                  // 0,1
    const int u4   = lane & 31;                  // float4 slot in 128-float row
    const int s0   = wave * 2;

    // Wave-uniform segment bounds (tiny, L2-hot -> s_loads).
    const int kbeg = segstart[s0];
    const int kmid = segstart[s0 + 1];
    const int kend = segstart[s0 + 2];

    const float* zb = lds + zloc * ROW;          // + e.{x,y,z} selects tensor/row

    float4 st[6];                                // staged next z-pair (24 VGPR)

    // ---- helpers (static unroll -> all regs) ----
    auto LOAD = [&](int zp) {
#pragma unroll
        for (int t = 0; t < 3; ++t) {
            const float4* src = (const float4*)(t == 0 ? x0 : (t == 1 ? x1 : x2));
#pragma unroll
            for (int i = 0; i < 2; ++i) {
                const int local = i * THREADS + tid;        // 0..511 float4
                const int z = local >> 8;                   // 256 float4 per row
                const int r = local & 255;
                st[t * 2 + i] = src[(size_t)(zp * ZPB + z) * (ROW / 4) + r];
            }
        }
    };
    auto WRITE = [&]() {
#pragma unroll
        for (int t = 0; t < 3; ++t) {
            float4* dst = (float4*)lds + t * (ZPB * ROW / 4);
#pragma unroll
            for (int i = 0; i < 2; ++i) {
                const int local = i * THREADS + tid;
                dst[local] = st[t * 2 + i];
            }
        }
    };

    int zp = blockIdx.x;                         // < GRID <= NZP always
    LOAD(zp);
    WRITE();                                     // compiler staggers vmcnt waits
    __syncthreads();

    for (;;) {
        const int zpn = zp + (int)gridDim.x;
        const bool more = zpn < NZP;
        if (more) LOAD(zpn);                     // issue early: hides under compute

        // ---- compute current z-pair: flat dual-accumulator segment loop ----
        float4 acc0 = make_float4(0.f, 0.f, 0.f, 0.f);
        float4 acc1 = make_float4(0.f, 0.f, 0.f, 0.f);

        int4 e0 = table[__builtin_amdgcn_readfirstlane(kbeg < kend ? kbeg : 0)];
        float4 a0 = *(const float4*)(zb + e0.x + u4 * 4);
        float4 b0 = *(const float4*)(zb + e0.y + u4 * 4);
        float4 c0 = *(const float4*)(zb + e0.z + u4 * 4);

        for (int k = kbeg; k < kend; ++k) {
            const int kn = (k + 1 < kend) ? k + 1 : k;
            const int4 e1 = table[__builtin_amdgcn_readfirstlane(kn)];
            const float4 a1 = *(const float4*)(zb + e1.x + u4 * 4);
            const float4 b1 = *(const float4*)(zb + e1.y + u4 * 4);
            const float4 c1 = *(const float4*)(zb + e1.z + u4 * 4);

            const float w  = __int_as_float(e0.w);
            const float w0 = (k < kmid) ? w : 0.f;   // wave-uniform select
            const float w1 = w - w0;                 // complementary, 1 VALU op

            float4 p;
            p.x = a0.x * b0.x * c0.x;
            p.y = a0.y * b0.y * c0.y;
            p.z = a0.z * b0.z * c0.z;
            p.w = a0.w * b0.w * c0.w;
            acc0.x = fmaf(p.x, w0, acc0.x);
            acc0.y = fmaf(p.y, w0, acc0.y);
            acc0.z = fmaf(p.z, w0, acc0.z);
            acc0.w = fmaf(p.w, w0, acc0.w);
            acc1.x = fmaf(p.x, w1, acc1.x);
            acc1.y = fmaf(p.y, w1, acc1.y);
            acc1.z = fmaf(p.z, w1, acc1.z);
            acc1.w = fmaf(p.w, w1, acc1.w);

            e0 = e1; a0 = a1; b0 = b1; c0 = c1;
        }

        float* orow = out + (size_t)(zp * ZPB + zloc) * ROW;
        *(float4*)(orow + s0 * Un + u4 * 4) = acc0;
        *(float4*)(orow + (s0 + 1) * Un + u4 * 4) = acc1;

        __syncthreads();                         // all waves done reading lds
        if (!more) break;
        WRITE();                                 // vmcnt waits folded per-use
        __syncthreads();                         // staged pair visible
        zp = zpn;
    }
}

extern "C" void kernel_launch(void* const* d_in, const int* in_sizes, int n_in,
                              void* d_out, int out_size, void* d_ws, size_t ws_size,
                              hipStream_t stream) {
    const float* x0 = (const float*)d_in[0];
    const float* x1 = (const float*)d_in[1];
    const float* x2 = (const float*)d_in[2];
    const float* pc = (const float*)d_in[3];
    const int*   pi = (const int*)d_in[4];
    float* out = (float*)d_out;

    int4* table    = (int4*)d_ws;
    int*  segstart = (int*)((char*)d_ws + Pn * sizeof(int4));

    prep_kernel<<<1, 64, 0, stream>>>(pi, pc, table, segstart);
    tp_kernel<<<GRID, THREADS, 0, stream>>>(x0, x1, x2, table, segstart, out);
}

// Round 3
// 264.171 us; speedup vs baseline: 1.1164x; 1.1164x over previous
//
#include <hip/hip_runtime.h>
#include <stdint.h>

constexpr int Zn = 20000;
constexpr int Un = 128;
constexpr int Sn = 8;
constexpr int Pn = 64;
constexpr int ROW = Sn * Un;          // 1024 floats per (z, tensor)
constexpr int ZPB = 2;                // z rows per buffer
constexpr int NZP = Zn / ZPB;         // 10000 z-pair rounds
constexpr int THREADS = 512;          // 8 waves; wave w owns segment w
constexpr int GRID = 768;             // 3 blocks/CU x 256 CU, persistent
constexpr int BUFF = 3 * ZPB * ROW;   // 6144 floats = 24 KB per buffer

// ---------------------------------------------------------------------------
// Prep: one wave, one lane per path. Counting-sort by i3 via ballot/popc.
// Table entries hold LDS float offsets for layout [t][z][1024] and coef.
// ---------------------------------------------------------------------------
__global__ __launch_bounds__(64) void prep_kernel(const int* __restrict__ pi,
                                                  const float* __restrict__ pc,
                                                  int4* __restrict__ table,
                                                  int* __restrict__ segstart) {
    const int p = threadIdx.x & 63;
    const int i0 = pi[4 * p + 0];
    const int i1 = pi[4 * p + 1];
    const int i2 = pi[4 * p + 2];
    const int i3 = pi[4 * p + 3];
    const float w = pc[p];
    const unsigned long long below = (1ull << p) - 1ull;

    int base = 0, slot = 0;
#pragma unroll
    for (int s = 0; s < Sn; ++s) {
        unsigned long long m = __ballot(i3 == s);
        if (i3 == s) slot = base + __popcll(m & below);
        if (p == 0) segstart[s] = base;
        base += __popcll(m);
    }
    if (p == 0) segstart[Sn] = base;   // == 64

    table[slot] = make_int4(i0 * Un,                    // tensor0: offset 0
                            ZPB * ROW + i1 * Un,        // tensor1 section base
                            2 * ZPB * ROW + i2 * Un,    // tensor2 section base
                            __float_as_int(w));
}

// ---------------------------------------------------------------------------
// Main: persistent blocks (768 = 3/CU x 8 waves = 24 waves/CU), DOUBLE-
// BUFFERED LDS (2 x 24 KB) filled by global_load_lds DMA (no VGPR staging ->
// no spill, the R2 failure). Counted vmcnt(3) + raw s_barrier keeps the next
// round's 3 DMA loads in flight across the barrier while computing the
// current buffer (T3/T4 pattern). __syncthreads() is NOT used in the loop:
// it would emit vmcnt(0) and drain the prefetch.
// Path table lives in LDS so in-loop table reads are lgkmcnt (ds) ops and
// never perturb the counted vmcnt arithmetic.
// ---------------------------------------------------------------------------
__global__ __launch_bounds__(THREADS, 6) void tp_kernel(
        const float* __restrict__ x0,
        const float* __restrict__ x1,
        const float* __restrict__ x2,
        const int4* __restrict__ table,
        const int* __restrict__ segstart,
        float* __restrict__ out) {
    __shared__ __align__(16) float lds[2 * BUFF];   // 48 KB, [buf][t][z][1024]
    __shared__ __align__(16) int4 tbl[Pn];          // 1 KB path table

    const int tid  = threadIdx.x;
    const int lane = tid & 63;
    const int wave = tid >> 6;                   // 0..7: one segment each
    const int zloc = lane >> 5;                  // 0,1
    const int u4   = lane & 31;                  // float4 slot in 128-float row

    // Per-wave segment bounds (prologue global loads: issued before any DMA,
    // so FIFO retirement keeps the in-loop vmcnt counts exact).
    const int kbeg = segstart[wave];
    const int kend = segstart[wave + 1];
    if (tid < Pn) tbl[tid] = table[tid];         // compiler waits vmcnt here

    // Stage addressing: thread tid moves one float4 per tensor per round.
    const int zs = tid >> 8;                     // 0,1
    const int rs = tid & 255;                    // float4 within 1024-float row

    auto ISSUE = [&](int buf, int zp) {
#pragma unroll
        for (int t = 0; t < 3; ++t) {
            const float4* src = (const float4*)(t == 0 ? x0 : (t == 1 ? x1 : x2));
            const float4* g = src + (size_t)(zp * ZPB + zs) * (ROW / 4) + rs;
            float* l = lds + buf * BUFF + t * (ZPB * ROW) + tid * 4;
            __builtin_amdgcn_global_load_lds(
                (const __attribute__((address_space(1))) void*)g,
                (__attribute__((address_space(3))) void*)l, 16, 0, 0);
        }
    };

    int zp  = blockIdx.x;                        // GRID < NZP: every block works
    int cur = 0;
    ISSUE(0, zp);                                // 3 DMA loads in flight

    for (;;) {
        const int zpn = zp + GRID;
        const bool more = zpn < NZP;
        if (more) {
            ISSUE(cur ^ 1, zpn);                 // +3 loads: issued EARLY
            // wait until <=3 outstanding: current buffer's DMA (older) done,
            // next buffer's 3 still in flight across the barrier.
            asm volatile("s_waitcnt vmcnt(3)" ::: "memory");
        } else {
            asm volatile("s_waitcnt vmcnt(0)" ::: "memory");
        }
        __builtin_amdgcn_s_barrier();            // raw: no implicit vmcnt(0)
        asm volatile("" ::: "memory");

        // ---- compute current buffer: 1-deep software-pipelined k-loop ----
        const float* zb = lds + cur * BUFF + zloc * ROW;
        float4 acc = make_float4(0.f, 0.f, 0.f, 0.f);

        int4 e0 = tbl[kbeg < kend ? kbeg : 0];   // wave-uniform ds broadcast
        float4 a0 = *(const float4*)(zb + e0.x + u4 * 4);
        float4 b0 = *(const float4*)(zb + e0.y + u4 * 4);
        float4 c0 = *(const float4*)(zb + e0.z + u4 * 4);

        for (int k = kbeg; k < kend; ++k) {
            const int kn = (k + 1 < kend) ? k + 1 : k;
            const int4 e1 = tbl[kn];
            const float4 a1 = *(const float4*)(zb + e1.x + u4 * 4);
            const float4 b1 = *(const float4*)(zb + e1.y + u4 * 4);
            const float4 c1 = *(const float4*)(zb + e1.z + u4 * 4);

            const float w = __int_as_float(e0.w);
            acc.x = fmaf(a0.x * b0.x * c0.x, w, acc.x);
            acc.y = fmaf(a0.y * b0.y * c0.y, w, acc.y);
            acc.z = fmaf(a0.z * b0.z * c0.z, w, acc.z);
            acc.w = fmaf(a0.w * b0.w * c0.w, w, acc.w);

            e0 = e1; a0 = a1; b0 = b1; c0 = c1;
        }

        float* orow = out + (size_t)(zp * ZPB + zloc) * ROW;
        *(float4*)(orow + wave * Un + u4 * 4) = acc;

        asm volatile("" ::: "memory");
        __builtin_amdgcn_s_barrier();            // reads of buf[cur] done before
        if (!more) break;                        // next round's DMA overwrites it
        cur ^= 1;
        zp = zpn;
    }
}

extern "C" void kernel_launch(void* const* d_in, const int* in_sizes, int n_in,
                              void* d_out, int out_size, void* d_ws, size_t ws_size,
                              hipStream_t stream) {
    const float* x0 = (const float*)d_in[0];
    const float* x1 = (const float*)d_in[1];
    const float* x2 = (const float*)d_in[2];
    const float* pc = (const float*)d_in[3];
    const int*   pi = (const int*)d_in[4];
    float* out = (float*)d_out;

    int4* table    = (int4*)d_ws;
    int*  segstart = (int*)((char*)d_ws + Pn * sizeof(int4));

    prep_kernel<<<1, 64, 0, stream>>>(pi, pc, table, segstart);
    tp_kernel<<<GRID, THREADS, 0, stream>>>(x0, x1, x2, table, segstart, out);
}